// Round 2
// baseline (111.303 us; speedup 1.0000x reference)
//
#include <hip/hip_runtime.h>
#include <hip/hip_cooperative_groups.h>
#include <math.h>

namespace cg = cooperative_groups;

// Problem: out_matrix, label_matrix [n=64, n=64, B=256] f32.
// loss = sum_{b,r,j,k} relu(m - (o[r,j,b]-o[r,k,b])*(l[r,j,b]-l[r,k,b]))
// Symmetric in (j,k); diagonal = relu(m). So loss = 2*S_upper + N*N*B*relu(m).
// cnt = #{(b,r): argmax_j o[r,j,b] == argmax_j l[r,j,b]}
//
// V3: single cooperative launch (partial + grid.sync + fold) — removes the
// second dispatch and its gap. Argmax split across all 8 waves (8-long scans
// + 8-way fold) instead of a 63-iteration serial tail on wave 0.

constexpr int N = 64;        // n
constexpr int B = 256;       // batch (contiguous innermost)
constexpr int BCHUNK = 64;   // b's per block (== wave width -> jg wave-uniform)
constexpr int NJG = 8;       // j-groups (one per wave)
constexpr int JI = 8;        // j's per thread: j = jg + 8*i
constexpr int THREADS = BCHUNK * NJG;       // 512
constexpr int NBLK = N * (B / BCHUNK);      // 256 partials

__global__ __launch_bounds__(THREADS)
void pm_hinge_fused(const float* __restrict__ outm,
                    const float* __restrict__ labm,
                    const float* __restrict__ margin,
                    float* __restrict__ ws,
                    float* __restrict__ dout)
{
    __shared__ __align__(16) float2 s[N * BCHUNK];   // [j][b] {o,l}, 32 KB
    __shared__ __align__(16) float4 cand[NJG * 64];  // per-wave argmax cands, 8 KB
    __shared__ float wsum[NJG];

    const int r   = blockIdx.x;
    const int b0  = blockIdx.y * BCHUNK;
    const int t   = threadIdx.x;
    const int blk = blockIdx.y * N + r;   // 0..255

    // Stage global -> LDS, interleaving o/l into float2 pairs.
    const float* src_o = outm + (size_t)r * (N * B) + b0;
    const float* src_l = labm + (size_t)r * (N * B) + b0;
#pragma unroll
    for (int f = t; f < (N * BCHUNK) / 4; f += THREADS) {
        const int j  = f >> 4;
        const int b4 = (f & 15) * 4;
        const float4 o4 = *(const float4*)(src_o + j * B + b4);
        const float4 l4 = *(const float4*)(src_l + j * B + b4);
        float4* dst = (float4*)(&s[j * BCHUNK + b4]);
        dst[0] = make_float4(o4.x, l4.x, o4.y, l4.y);
        dst[1] = make_float4(o4.z, l4.z, o4.w, l4.w);
    }
    __syncthreads();

    const float m  = margin[0];
    const int   b  = t & 63;   // lane id == b -> natural b64 LDS pattern
    const int   jg = t >> 6;   // wave id == j-group (wave-uniform)

    float oj[JI], lj[JI];
#pragma unroll
    for (int i = 0; i < JI; ++i) {
        const float2 v = s[(jg + NJG * i) * BCHUNK + b];
        oj[i] = v.x; lj[i] = v.y;
    }

    // Per-wave argmax candidates: wave jg scans j in [8*jg, 8*jg+8).
    // Strict > keeps first-occurrence semantics within the ascending scan.
    {
        const int jbase = jg * 8;
        float2 v = s[jbase * BCHUNK + b];
        float bo = v.x; int io = jbase;
        float bl = v.y; int il = jbase;
#pragma unroll
        for (int jj = 1; jj < 8; ++jj) {
            v = s[(jbase + jj) * BCHUNK + b];
            if (v.x > bo) { bo = v.x; io = jbase + jj; }
            if (v.y > bl) { bl = v.y; il = jbase + jj; }
        }
        cand[jg * 64 + b] = make_float4(bo, __int_as_float(io),
                                        bl, __int_as_float(il));
    }

    // Strict upper triangle, balanced by strided j-assignment.
    // Regime mr (0..7): k in [jg+8*mr+1, jg+8*mr+8] (mr=7 clips at 63) has
    // exactly mr+1 of this thread's j's with j < k. Wave-uniform bounds.
    float acc0 = 0.0f, acc1 = 0.0f;
#pragma unroll
    for (int mr = 0; mr < 8; ++mr) {
        const int kbeg = jg + 8 * mr + 1;
        const int kend = (mr == 7) ? N : (jg + 8 * mr + 9);   // exclusive
#pragma unroll 4
        for (int k = kbeg; k < kend; ++k) {
            const float2 v = s[k * BCHUNK + b];   // one ds_read_b64
            const float ok = v.x, lk = v.y;
#pragma unroll
            for (int i = 0; i <= mr; ++i) {
                const float tv = fmaxf(fmaf(ok - oj[i], lj[i] - lk, m), 0.0f);
                if (i & 1) acc1 += tv; else acc0 += tv;
            }
        }
    }
    float acc = acc0 + acc1;

    // Per-wave shuffle reduce of the hinge partial.
#pragma unroll
    for (int off = 32; off > 0; off >>= 1)
        acc += __shfl_down(acc, off, 64);
    if (b == 0) wsum[jg] = acc;
    __syncthreads();

    // Wave 0: fold the 8 argmax candidates per b (ascending wave order +
    // strict > preserves first-occurrence) and the 8 wave partials.
    if (t < 64) {
        float4 c0 = cand[t];
        float bo = c0.x; int io = __float_as_int(c0.y);
        float bl = c0.z; int il = __float_as_int(c0.w);
#pragma unroll
        for (int w = 1; w < NJG; ++w) {
            const float4 cw = cand[w * 64 + t];
            if (cw.x > bo) { bo = cw.x; io = __float_as_int(cw.y); }
            if (cw.z > bl) { bl = cw.z; il = __float_as_int(cw.w); }
        }
        const unsigned long long mask = __ballot(io == il);
        if (t == 0) {
            float ssum = 0.0f;
#pragma unroll
            for (int w = 0; w < NJG; ++w) ssum += wsum[w];
            ws[blk] = ssum;                         // upper-triangle partial
            ws[NBLK + blk] = (float)__popcll(mask); // argmax-equality partial
            __threadfence();                        // device-scope visibility
        }
    }

    // Grid-wide barrier, then block (0,0) folds all 256 partials.
    cg::this_grid().sync();

    if (blockIdx.x == 0 && blockIdx.y == 0 && t < 64) {
        float ssum = 0.0f, c = 0.0f;
#pragma unroll
        for (int i = 0; i < NBLK / 64; ++i) {
            ssum += ws[t + 64 * i];
            c    += ws[NBLK + t + 64 * i];
        }
#pragma unroll
        for (int off = 32; off > 0; off >>= 1) {
            ssum += __shfl_down(ssum, off, 64);
            c    += __shfl_down(c, off, 64);
        }
        if (t == 0) {
            dout[0] = 2.0f * ssum + (float)(N * (size_t)N * B) * fmaxf(m, 0.0f);
            dout[1] = c;
        }
    }
}

extern "C" void kernel_launch(void* const* d_in, const int* in_sizes, int n_in,
                              void* d_out, int out_size, void* d_ws, size_t ws_size,
                              hipStream_t stream) {
    const float* outm   = (const float*)d_in[0];
    const float* labm   = (const float*)d_in[1];
    const float* margin = (const float*)d_in[2];
    float* out = (float*)d_out;
    float* ws  = (float*)d_ws;

    void* args[] = { (void*)&outm, (void*)&labm, (void*)&margin,
                     (void*)&ws, (void*)&out };
    hipLaunchCooperativeKernel((const void*)pm_hinge_fused,
                               dim3(N, B / BCHUNK), dim3(THREADS),
                               args, 0, stream);
}

// Round 3
// 68.896 us; speedup vs baseline: 1.6155x; 1.6155x over previous
//
#include <hip/hip_runtime.h>
#include <math.h>

// Problem: out_matrix, label_matrix [n=64, n=64, B=256] f32.
// loss = sum_{b,r,j,k} relu(m - (o[r,j,b]-o[r,k,b])*(l[r,j,b]-l[r,k,b]))
// Symmetric in (j,k); diagonal = relu(m). So loss = 2*S_upper + N*N*B*relu(m).
// cnt = #{(b,r): argmax_j o[r,j,b] == argmax_j l[r,j,b]}
//
// V4: revert to two plain dispatches (V3's cooperative launch cost +42 us of
// launch overhead). Keep V2's float2-interleaved LDS (one ds_read_b64 per k,
// 8 FMA terms amortized) and V3's wave-parallel argmax (8-long scan per wave
// + wave-0 fold, instead of a 63-iter serial tail on wave 0).

constexpr int N = 64;        // n
constexpr int B = 256;       // batch (contiguous innermost)
constexpr int BCHUNK = 64;   // b's per block (== wave width -> jg wave-uniform)
constexpr int NJG = 8;       // j-groups (one per wave)
constexpr int JI = 8;        // j's per thread: j = jg + 8*i
constexpr int THREADS = BCHUNK * NJG;       // 512
constexpr int NBLK = N * (B / BCHUNK);      // 256 partials

__global__ __launch_bounds__(THREADS)
void pm_hinge_partial(const float* __restrict__ outm,
                      const float* __restrict__ labm,
                      const float* __restrict__ margin,
                      float* __restrict__ ws)
{
    __shared__ __align__(16) float2 s[N * BCHUNK];   // [j][b] {o,l}, 32 KB
    __shared__ __align__(16) float4 cand[NJG * 64];  // per-wave argmax cands, 8 KB
    __shared__ float wsum[NJG];

    const int r   = blockIdx.x;
    const int b0  = blockIdx.y * BCHUNK;
    const int t   = threadIdx.x;
    const int blk = blockIdx.y * N + r;   // 0..255

    // Stage global -> LDS, interleaving o/l into float2 pairs.
    const float* src_o = outm + (size_t)r * (N * B) + b0;
    const float* src_l = labm + (size_t)r * (N * B) + b0;
#pragma unroll
    for (int f = t; f < (N * BCHUNK) / 4; f += THREADS) {
        const int j  = f >> 4;
        const int b4 = (f & 15) * 4;
        const float4 o4 = *(const float4*)(src_o + j * B + b4);
        const float4 l4 = *(const float4*)(src_l + j * B + b4);
        float4* dst = (float4*)(&s[j * BCHUNK + b4]);
        dst[0] = make_float4(o4.x, l4.x, o4.y, l4.y);
        dst[1] = make_float4(o4.z, l4.z, o4.w, l4.w);
    }
    __syncthreads();

    const float m  = margin[0];
    const int   b  = t & 63;   // lane id == b -> natural b64 LDS pattern
    const int   jg = t >> 6;   // wave id == j-group (wave-uniform)

    float oj[JI], lj[JI];
#pragma unroll
    for (int i = 0; i < JI; ++i) {
        const float2 v = s[(jg + NJG * i) * BCHUNK + b];
        oj[i] = v.x; lj[i] = v.y;
    }

    // Per-wave argmax candidates: wave jg scans j in [8*jg, 8*jg+8).
    // Strict > keeps first-occurrence semantics within the ascending scan.
    {
        const int jbase = jg * 8;
        float2 v = s[jbase * BCHUNK + b];
        float bo = v.x; int io = jbase;
        float bl = v.y; int il = jbase;
#pragma unroll
        for (int jj = 1; jj < 8; ++jj) {
            v = s[(jbase + jj) * BCHUNK + b];
            if (v.x > bo) { bo = v.x; io = jbase + jj; }
            if (v.y > bl) { bl = v.y; il = jbase + jj; }
        }
        cand[jg * 64 + b] = make_float4(bo, __int_as_float(io),
                                        bl, __int_as_float(il));
    }

    // Strict upper triangle, balanced by strided j-assignment.
    // Regime mr (0..7): k in [jg+8*mr+1, jg+8*mr+8] (mr=7 clips at 63) has
    // exactly mr+1 of this thread's j's with j < k. Wave-uniform bounds.
    float acc0 = 0.0f, acc1 = 0.0f;
#pragma unroll
    for (int mr = 0; mr < 8; ++mr) {
        const int kbeg = jg + 8 * mr + 1;
        const int kend = (mr == 7) ? N : (jg + 8 * mr + 9);   // exclusive
#pragma unroll 4
        for (int k = kbeg; k < kend; ++k) {
            const float2 v = s[k * BCHUNK + b];   // one ds_read_b64
            const float ok = v.x, lk = v.y;
#pragma unroll
            for (int i = 0; i <= mr; ++i) {
                const float tv = fmaxf(fmaf(ok - oj[i], lj[i] - lk, m), 0.0f);
                if (i & 1) acc1 += tv; else acc0 += tv;
            }
        }
    }
    float acc = acc0 + acc1;

    // Per-wave shuffle reduce of the hinge partial.
#pragma unroll
    for (int off = 32; off > 0; off >>= 1)
        acc += __shfl_down(acc, off, 64);
    if (b == 0) wsum[jg] = acc;
    __syncthreads();

    // Wave 0: fold the 8 argmax candidates per b (ascending wave order +
    // strict > preserves first-occurrence) and the 8 wave partials.
    if (t < 64) {
        float4 c0 = cand[t];
        float bo = c0.x; int io = __float_as_int(c0.y);
        float bl = c0.z; int il = __float_as_int(c0.w);
#pragma unroll
        for (int w = 1; w < NJG; ++w) {
            const float4 cw = cand[w * 64 + t];
            if (cw.x > bo) { bo = cw.x; io = __float_as_int(cw.y); }
            if (cw.z > bl) { bl = cw.z; il = __float_as_int(cw.w); }
        }
        const unsigned long long mask = __ballot(io == il);
        if (t == 0) {
            float ssum = 0.0f;
#pragma unroll
            for (int w = 0; w < NJG; ++w) ssum += wsum[w];
            ws[blk] = ssum;                         // upper-triangle partial
            ws[NBLK + blk] = (float)__popcll(mask); // argmax-equality partial
        }
    }
}

// One wave: fold 256+256 partials, apply symmetry factor + diagonal.
__global__ __launch_bounds__(64)
void pm_hinge_reduce(const float* __restrict__ ws,
                     const float* __restrict__ margin,
                     float* __restrict__ dout)
{
    const int t = threadIdx.x;
    float s = 0.0f, c = 0.0f;
#pragma unroll
    for (int i = 0; i < NBLK / 64; ++i) {
        s += ws[t + 64 * i];
        c += ws[NBLK + t + 64 * i];
    }
#pragma unroll
    for (int off = 32; off > 0; off >>= 1) {
        s += __shfl_down(s, off, 64);
        c += __shfl_down(c, off, 64);
    }
    if (t == 0) {
        const float m = margin[0];
        dout[0] = 2.0f * s + (float)(N * (size_t)N * B) * fmaxf(m, 0.0f);
        dout[1] = c;
    }
}

extern "C" void kernel_launch(void* const* d_in, const int* in_sizes, int n_in,
                              void* d_out, int out_size, void* d_ws, size_t ws_size,
                              hipStream_t stream) {
    const float* outm   = (const float*)d_in[0];
    const float* labm   = (const float*)d_in[1];
    const float* margin = (const float*)d_in[2];
    float* out = (float*)d_out;
    float* ws  = (float*)d_ws;

    pm_hinge_partial<<<dim3(N, B / BCHUNK), THREADS, 0, stream>>>(outm, labm, margin, ws);
    pm_hinge_reduce<<<1, 64, 0, stream>>>(ws, margin, out);
}